// Round 6
// baseline (507.173 us; speedup 1.0000x reference)
//
#include <hip/hip_runtime.h>
#include <hip/hip_bf16.h>
#include <stdint.h>

// Problem constants
#define B_    2
#define S_    2048
#define HID_  2048
#define H_    16
#define KV_   2
#define D_    128
#define ROT_  32
#define NQG   4096   // H*2D
#define NKV   256    // KV*D
#define SCALE_ 0.08838834764831845f  // D^-0.5

typedef __attribute__((ext_vector_type(8))) short  short8;
typedef __attribute__((ext_vector_type(4))) float  floatx4;

__device__ __forceinline__ float b2f(unsigned short u) {
  union { unsigned int i; float f; } v; v.i = ((unsigned int)u) << 16; return v.f;
}
__device__ __forceinline__ unsigned short f2b(float f) {
  union { float f; unsigned int i; } v; v.f = f;
  return (unsigned short)((v.i + 0x7fffu + ((v.i >> 16) & 1u)) >> 16);
}

// ---------------- fp32 -> bf16 elementwise convert (8 elems/thread) ----------------
__global__ __launch_bounds__(256) void k_cvt(const float* __restrict__ in,
                                             unsigned short* __restrict__ out, long n) {
  long i0 = ((long)blockIdx.x * 256 + threadIdx.x) * 8;
  if (i0 >= n) return;
  float4 a = *(const float4*)(in + i0);
  float4 b = *(const float4*)(in + i0 + 4);
  short8 v;
  v[0] = (short)f2b(a.x); v[1] = (short)f2b(a.y);
  v[2] = (short)f2b(a.z); v[3] = (short)f2b(a.w);
  v[4] = (short)f2b(b.x); v[5] = (short)f2b(b.y);
  v[6] = (short)f2b(b.z); v[7] = (short)f2b(b.w);
  *(short8*)(out + i0) = v;
}

// ---------------- prep: gamma/eta (identical) + folded key bias ----------------
__global__ __launch_bounds__(256) void k_prep(const float* __restrict__ prior,
                                              float* __restrict__ ge,
                                              float* __restrict__ kbias) {
  int i = blockIdx.x * 256 + threadIdx.x;
  if (i >= S_) return;
  float p  = prior[i];
  float pc = p * (float)S_;
  float g  = 1.0f + 0.1f * (pc - 1.0f);
  g = fminf(fmaxf(g, 0.9f), 1.1f);
  ge[i] = g;
  float cb = fminf(fmaxf(p, -3.0f), 3.0f);          // clip(BETA_BIAS*prior, -3, 3)
  kbias[i] = cb + logf(1.0f + 0.5f * pc);           // + ln(1 + BETA_POST*pc)
}

// ---------------- transpose + convert: out_bf16[C][R] = in_fp32[R][C] ----------------
__global__ __launch_bounds__(256) void k_transpose(const float* __restrict__ in,
                                                   unsigned short* __restrict__ out,
                                                   int R, int C) {
  __shared__ unsigned short tile[64][68];
  int tx = threadIdx.x & 15, ty = threadIdx.x >> 4;
  long c0 = (long)blockIdx.x * 64, r0 = (long)blockIdx.y * 64;
#pragma unroll
  for (int i = 0; i < 4; i++) {
    int row = ty + 16 * i;
    const float* src = in + (r0 + row) * C + c0 + 4 * tx;
    float4 v = *(const float4*)src;
    tile[row][4 * tx + 0] = f2b(v.x);
    tile[row][4 * tx + 1] = f2b(v.y);
    tile[row][4 * tx + 2] = f2b(v.z);
    tile[row][4 * tx + 3] = f2b(v.w);
  }
  __syncthreads();
#pragma unroll
  for (int i = 0; i < 4; i++) {
    int oc = ty + 16 * i;
    ushort4 v;
    v.x = tile[4 * tx + 0][oc];
    v.y = tile[4 * tx + 1][oc];
    v.z = tile[4 * tx + 2][oc];
    v.w = tile[4 * tx + 3][oc];
    *(ushort4*)(out + (c0 + oc) * R + r0 + 4 * tx) = v;
  }
}

// ---------------- GEMM: C[M][N] = A[M][K] @ Bt[N][K]^T  (bf16 in, fp32 acc) ----------------
// OUT32=0: bf16 output; OUT32=1: fp32 output.
// 128x128 tile, BK=32, 4 waves (2x2), reg-staged LDS (pad 40 elems/row), prefetch.
template <int OUT32>
__global__ __launch_bounds__(256) void k_gemm_bt(const unsigned short* __restrict__ A,
                                                 const unsigned short* __restrict__ Bt,
                                                 void* __restrict__ Cv,
                                                 int M, int N, int K) {
  __shared__ __align__(16) unsigned short As[128 * 40];
  __shared__ __align__(16) unsigned short Bs[128 * 40];
  const int t    = threadIdx.x;
  const int lane = t & 63;
  const int wv   = t >> 6;
  const int wm   = wv >> 1, wn = wv & 1;
  const long m0  = (long)blockIdx.y * 128;
  const long n0  = (long)blockIdx.x * 128;
  const int r15  = lane & 15, g4 = lane >> 4;
  const int row0 = t >> 2, cb = t & 3;

  const unsigned short* Ap0 = A  + (m0 + row0)      * K + cb * 8;
  const unsigned short* Ap1 = A  + (m0 + row0 + 64) * K + cb * 8;
  const unsigned short* Bp0 = Bt + (n0 + row0)      * K + cb * 8;
  const unsigned short* Bp1 = Bt + (n0 + row0 + 64) * K + cb * 8;

  floatx4 acc[4][4];
#pragma unroll
  for (int m = 0; m < 4; m++)
#pragma unroll
    for (int n = 0; n < 4; n++) acc[m][n] = (floatx4){0.f, 0.f, 0.f, 0.f};

  short8 va0 = *(const short8*)(Ap0);
  short8 va1 = *(const short8*)(Ap1);
  short8 vb0 = *(const short8*)(Bp0);
  short8 vb1 = *(const short8*)(Bp1);

  for (int k0 = 0; k0 < K; k0 += 32) {
    *(short8*)(&As[row0 * 40 + cb * 8])        = va0;
    *(short8*)(&As[(row0 + 64) * 40 + cb * 8]) = va1;
    *(short8*)(&Bs[row0 * 40 + cb * 8])        = vb0;
    *(short8*)(&Bs[(row0 + 64) * 40 + cb * 8]) = vb1;
    __syncthreads();
    if (k0 + 32 < K) {  // prefetch next K-step while MFMAs run
      va0 = *(const short8*)(Ap0 + k0 + 32);
      va1 = *(const short8*)(Ap1 + k0 + 32);
      vb0 = *(const short8*)(Bp0 + k0 + 32);
      vb1 = *(const short8*)(Bp1 + k0 + 32);
    }
    short8 af[4], bf[4];
#pragma unroll
    for (int m = 0; m < 4; m++)
      af[m] = *(const short8*)(&As[(wm * 64 + m * 16 + r15) * 40 + g4 * 8]);
#pragma unroll
    for (int n = 0; n < 4; n++)
      bf[n] = *(const short8*)(&Bs[(wn * 64 + n * 16 + r15) * 40 + g4 * 8]);
#pragma unroll
    for (int m = 0; m < 4; m++)
#pragma unroll
      for (int n = 0; n < 4; n++)
        acc[m][n] = __builtin_amdgcn_mfma_f32_16x16x32_bf16(af[m], bf[n], acc[m][n], 0, 0, 0);
    __syncthreads();
  }

#pragma unroll
  for (int m = 0; m < 4; m++) {
    const long rbase = m0 + wm * 64 + m * 16 + g4 * 4;
#pragma unroll
    for (int n = 0; n < 4; n++) {
      const long cidx = n0 + wn * 64 + n * 16 + r15;
#pragma unroll
      for (int i = 0; i < 4; i++) {
        if (OUT32) ((float*)Cv)[(rbase + i) * N + cidx] = acc[m][n][i];
        else ((unsigned short*)Cv)[(rbase + i) * N + cidx] = f2b(acc[m][n][i]);
      }
    }
  }
}

// ---------------- q/k postprocess: RMS norm + RoPE (+gamma for k), one wave per (b,s,head) ----------------
__global__ __launch_bounds__(256) void k_qkpost(const unsigned short* __restrict__ qg,
                                                const unsigned short* __restrict__ kraw,
                                                const float* __restrict__ cosb,
                                                const float* __restrict__ sinb,
                                                const float* __restrict__ ge,
                                                const float* __restrict__ qnw,
                                                const float* __restrict__ knw,
                                                unsigned short* __restrict__ qT,
                                                unsigned short* __restrict__ kT) {
  int wid  = (blockIdx.x * 256 + threadIdx.x) >> 6;
  int lane = threadIdx.x & 63;
  int r    = wid % (H_ + KV_);
  long bs  = wid / (H_ + KV_);
  if (bs >= (long)B_ * S_) return;
  int b = (int)(bs >> 11), s = (int)(bs & 2047);
  int d0 = lane * 2;

  float x0, x1;
  if (r < H_) {
    const unsigned short* src = qg + bs * NQG + r * 256 + d0;
    x0 = b2f(src[0]); x1 = b2f(src[1]);
  } else {
    const unsigned short* src = kraw + bs * NKV + (r - H_) * 128 + d0;
    x0 = b2f(src[0]); x1 = b2f(src[1]);
  }
  float ss = x0 * x0 + x1 * x1;
#pragma unroll
  for (int mask = 1; mask < 64; mask <<= 1) ss += __shfl_xor(ss, mask);
  float rstd = rsqrtf(ss * (1.0f / 128.0f) + 1e-6f);
  float w0, w1;
  if (r < H_) { w0 = qnw[d0]; w1 = qnw[d0 + 1]; }
  else        { w0 = knw[d0]; w1 = knw[d0 + 1]; }
  float xn0 = x0 * rstd * w0, xn1 = x1 * rstd * w1;
  float p0 = __shfl_xor(xn0, 8), p1 = __shfl_xor(xn1, 8);
  float y0 = xn0, y1 = xn1;
  if (lane < 16) {  // d0 < 32 : RoPE region
    float c0 = cosb[bs * ROT_ + d0], c1 = cosb[bs * ROT_ + d0 + 1];
    float s0 = sinb[bs * ROT_ + d0], s1 = sinb[bs * ROT_ + d0 + 1];
    float sgn = (lane < 8) ? -1.0f : 1.0f;  // rot_half: d<16 gets -x[d+16]*sin, 16<=d<32 gets +x[d-16]*sin
    y0 = xn0 * c0 + sgn * p0 * s0;
    y1 = xn1 * c1 + sgn * p1 * s1;
  }
  unsigned int pack;
  if (r < H_) {
    pack = (unsigned int)f2b(y0) | ((unsigned int)f2b(y1) << 16);
    *(unsigned int*)(qT + ((long)(b * H_ + r) * S_ + s) * D_ + d0) = pack;
  } else {
    float g = ge[s];
    pack = (unsigned int)f2b(y0 * g) | ((unsigned int)f2b(y1 * g) << 16);
    *(unsigned int*)(kT + ((long)(b * KV_ + (r - H_)) * S_ + s) * D_ + d0) = pack;
  }
}

// ---------------- v postprocess: scale by eta, write transposed vT[b][kv][d][s] ----------------
__global__ __launch_bounds__(256) void k_vpost(const unsigned short* __restrict__ vraw,
                                               const float* __restrict__ ge,
                                               unsigned short* __restrict__ vT) {
  int bx  = blockIdx.x;
  int scn = bx & 7, d = (bx >> 3) & 127, kvb = (bx >> 10) & 1, b = bx >> 11;
  int s = scn * 256 + threadIdx.x;
  float v = b2f(vraw[((long)(b * S_ + s)) * NKV + kvb * 128 + d]);
  v *= ge[s];
  vT[((long)(b * KV_ + kvb) * D_ + d) * S_ + s] = f2b(v);
}

// ---------------- flash attention, 1 wave/block, 16-row q-strip, swapped QK^T, defer-max ----------------
// Swapped MFMA: sacc = mfma(A=Kfrag, B=Qfrag) -> S[key = g4*4+i (+n*16)][q = r15].
// Each lane holds a full 16..64-key slice of ONE q-row => row reduce = in-reg + 2 shfl_xor.
// Rescale (and its lane broadcasts) deferred unless pmax > m + 8 (T13).
__global__ __launch_bounds__(64) void k_attn(const unsigned short* __restrict__ qT,
                                             const unsigned short* __restrict__ kT,
                                             const unsigned short* __restrict__ vT,
                                             const float* __restrict__ kbias,
                                             const unsigned short* __restrict__ qg,
                                             unsigned short* __restrict__ ag) {
  __shared__ __align__(16) unsigned short Ps[16 * 88];  // P tile [q=16][key=64], pad 88
  const int lane = threadIdx.x;
  const int r15 = lane & 15, g4 = lane >> 4;
  // XCD-grouped decode: xcd pair owns one (b,kvh); heavy strips dispatched first.
  const int p = blockIdx.x;
  const int xcd = p & 7;
  const int g = xcd >> 1;                               // 0..3 -> (b,kvh)
  const int member = ((p >> 3) << 1) | (xcd & 1);       // 0..1023 within group
  const int bh_local = member & 7;
  const int strip = 127 - (member >> 3);                // heavy q-strips first
  const int b = g >> 1, kvh = g & 1;
  const int hh = kvh * 8 + bh_local;
  const int q0s = strip * 16;
  const unsigned short* qbase = qT + ((long)(b * H_ + hh) * S_) * D_;
  const unsigned short* kbase = kT + ((long)(b * KV_ + kvh) * S_) * D_;
  const unsigned short* vbase = vT + ((long)(b * KV_ + kvh) * D_) * S_;

  short8 qf[4];
  {
    const unsigned short* qp = qbase + (long)(q0s + r15) * D_ + g4 * 8;
#pragma unroll
    for (int kb = 0; kb < 4; kb++) qf[kb] = *(const short8*)(qp + kb * 32);
  }

  floatx4 oacc[8];
#pragma unroll
  for (int nd = 0; nd < 8; nd++) oacc[nd] = (floatx4){0.f, 0.f, 0.f, 0.f};
  float mrow = -1e30f, lrow = 0.f;   // stats for q = q0s + r15 (replicated across g4)

  const int ntiles = (strip >> 2) + 1;  // causal: key tiles j0 <= strip*16
  for (int tile = 0; tile < ntiles; tile++) {
    const int j0 = tile * 64;

    // QK^T swapped: A = K fragment (rows=key), B = Q fragment (rows=q)
    floatx4 sacc[4];
#pragma unroll
    for (int n = 0; n < 4; n++) sacc[n] = (floatx4){0.f, 0.f, 0.f, 0.f};
#pragma unroll
    for (int n = 0; n < 4; n++) {
      const unsigned short* kp = kbase + (long)(j0 + n * 16 + r15) * D_ + g4 * 8;
#pragma unroll
      for (int kb = 0; kb < 4; kb++) {
        short8 ak = *(const short8*)(kp + kb * 32);
        sacc[n] = __builtin_amdgcn_mfma_f32_16x16x32_bf16(ak, qf[kb], sacc[n], 0, 0, 0);
      }
    }

    // scores: scf[n][i] = S[key = j0+n*16+g4*4+i][q = q0s+r15]
    float4 kb4[4];
#pragma unroll
    for (int n = 0; n < 4; n++) kb4[n] = *(const float4*)(&kbias[j0 + n * 16 + g4 * 4]);
    float scf[4][4];
    const bool last = (tile == ntiles - 1);
#pragma unroll
    for (int n = 0; n < 4; n++) {
#pragma unroll
      for (int i = 0; i < 4; i++) {
        float kbv = (i == 0) ? kb4[n].x : (i == 1) ? kb4[n].y : (i == 2) ? kb4[n].z : kb4[n].w;
        float v = sacc[n][i] * SCALE_ + kbv;
        if (last) {
          int jg = j0 + n * 16 + g4 * 4 + i;
          if (jg > q0s + r15) v = -1e30f;
        }
        scf[n][i] = v;
      }
    }

    // row max: 15 in-reg + 2 shfl
    float pmax = scf[0][0];
#pragma unroll
    for (int n = 0; n < 4; n++)
#pragma unroll
      for (int i = 0; i < 4; i++) pmax = fmaxf(pmax, scf[n][i]);
    pmax = fmaxf(pmax, __shfl_xor(pmax, 16));
    pmax = fmaxf(pmax, __shfl_xor(pmax, 32));

    // defer-max rescale (wave-uniform branch)
    if (__any(pmax > mrow + 8.0f)) {
      float mn = fmaxf(mrow, pmax);
      float aq = __expf(mrow - mn);
      mrow = mn;
      lrow *= aq;
      float ai[4];
#pragma unroll
      for (int i = 0; i < 4; i++) ai[i] = __shfl(aq, g4 * 4 + i);
#pragma unroll
      for (int nd = 0; nd < 8; nd++)
#pragma unroll
        for (int i = 0; i < 4; i++) oacc[nd][i] *= ai[i];
    }

    float rsum = 0.f;
#pragma unroll
    for (int n = 0; n < 4; n++)
#pragma unroll
      for (int i = 0; i < 4; i++) {
        float pv = __expf(scf[n][i] - mrow);
        scf[n][i] = pv;
        rsum += pv;
      }
    rsum += __shfl_xor(rsum, 16);
    rsum += __shfl_xor(rsum, 32);
    lrow += rsum;

    // P -> LDS (4 x ds_write_b64), then A-fragments (2 x ds_read_b128)
#pragma unroll
    for (int n = 0; n < 4; n++) {
      unsigned int lo = (unsigned int)f2b(scf[n][0]) | ((unsigned int)f2b(scf[n][1]) << 16);
      unsigned int hi = (unsigned int)f2b(scf[n][2]) | ((unsigned int)f2b(scf[n][3]) << 16);
      uint2 w; w.x = lo; w.y = hi;
      *(uint2*)(&Ps[r15 * 88 + n * 16 + g4 * 4]) = w;
    }

#pragma unroll
    for (int kb = 0; kb < 2; kb++) {
      short8 pa = *(const short8*)(&Ps[r15 * 88 + kb * 32 + g4 * 8]);
#pragma unroll
      for (int nd = 0; nd < 8; nd++) {
        short8 bv = *(const short8*)(vbase + (long)(nd * 16 + r15) * S_ + j0 + kb * 32 + g4 * 8);
        oacc[nd] = __builtin_amdgcn_mfma_f32_16x16x32_bf16(pa, bv, oacc[nd], 0, 0, 0);
      }
    }
  }

  // epilogue: broadcast l for q = g4*4+i, fuse sigmoid gate, write ag[b][s][h*D+d]
  float il[4];
#pragma unroll
  for (int i = 0; i < 4; i++) il[i] = __shfl(lrow, g4 * 4 + i);
#pragma unroll
  for (int i = 0; i < 4; i++) {
    int q = q0s + g4 * 4 + i;
    float inv = 1.0f / il[i];
    const unsigned short* gptr = qg + ((long)(b * S_ + q)) * NQG + hh * 256 + 128;
    unsigned short* aptr = ag + ((long)(b * S_ + q)) * (H_ * D_) + hh * D_;
#pragma unroll
    for (int nd = 0; nd < 8; nd++) {
      int d = nd * 16 + r15;
      float gt = b2f(gptr[d]);
      float sg = 1.0f / (1.0f + __expf(-gt));
      aptr[d] = f2b(oacc[nd][i] * inv * sg);
    }
  }
}

extern "C" void kernel_launch(void* const* d_in, const int* in_sizes, int n_in,
                              void* d_out, int out_size, void* d_ws, size_t ws_size,
                              hipStream_t stream) {
  const float* h_f   = (const float*)d_in[0];
  const float* cosb  = (const float*)d_in[1];
  const float* sinb  = (const float*)d_in[2];
  // d_in[3] = attention_mask : pure causal, applied analytically
  const float* prior = (const float*)d_in[4];
  const float* Wq    = (const float*)d_in[5];
  const float* Wk    = (const float*)d_in[6];
  const float* Wv    = (const float*)d_in[7];
  const float* Wo    = (const float*)d_in[8];
  const float* qnw   = (const float*)d_in[9];
  const float* knw   = (const float*)d_in[10];

  char* ws = (char*)d_ws;
  size_t off = 0;
  auto alloc = [&](size_t bytes) { char* p = ws + off; off += (bytes + 255) & ~(size_t)255; return p; };
  unsigned short* hb   = (unsigned short*)alloc((size_t)4096 * 2048 * 2);
  unsigned short* WqT  = (unsigned short*)alloc((size_t)4096 * 2048 * 2);
  unsigned short* WkT  = (unsigned short*)alloc((size_t)256 * 2048 * 2);
  unsigned short* WvT  = (unsigned short*)alloc((size_t)256 * 2048 * 2);
  unsigned short* WoT  = (unsigned short*)alloc((size_t)2048 * 2048 * 2);
  unsigned short* qg   = (unsigned short*)alloc((size_t)4096 * 4096 * 2);
  unsigned short* kraw = (unsigned short*)alloc((size_t)4096 * 256 * 2);
  unsigned short* vraw = (unsigned short*)alloc((size_t)4096 * 256 * 2);
  unsigned short* qTb  = (unsigned short*)alloc((size_t)B_ * H_ * S_ * D_ * 2);
  unsigned short* kTb  = (unsigned short*)alloc((size_t)B_ * KV_ * S_ * D_ * 2);
  unsigned short* vTb  = (unsigned short*)alloc((size_t)B_ * KV_ * S_ * D_ * 2);
  float* ge    = (float*)alloc((size_t)S_ * 4);
  float* kbias = (float*)alloc((size_t)S_ * 4);
  // Aliasing (sequential stream order makes these safe):
  // ag reuses hb (hb dead after the three projection GEMMs; k_attn reads qTb/kTb/vTb/qg only).
  unsigned short* ag = hb;

  dim3 blk(256);
  k_prep<<<dim3(8), blk, 0, stream>>>(prior, ge, kbias);
  k_cvt<<<dim3(4096), blk, 0, stream>>>(h_f, hb, (long)4096 * 2048);
  k_transpose<<<dim3(64, 32), blk, 0, stream>>>(Wq, WqT, 2048, 4096);
  k_transpose<<<dim3(4, 32),  blk, 0, stream>>>(Wk, WkT, 2048, 256);
  k_transpose<<<dim3(4, 32),  blk, 0, stream>>>(Wv, WvT, 2048, 256);
  k_transpose<<<dim3(32, 32), blk, 0, stream>>>(Wo, WoT, 2048, 2048);
  k_gemm_bt<0><<<dim3(32, 32), blk, 0, stream>>>(hb, WqT, qg,   4096, 4096, 2048);
  k_gemm_bt<0><<<dim3(2, 32),  blk, 0, stream>>>(hb, WkT, kraw, 4096, 256,  2048);
  k_gemm_bt<0><<<dim3(2, 32),  blk, 0, stream>>>(hb, WvT, vraw, 4096, 256,  2048);
  k_qkpost<<<dim3(18432), blk, 0, stream>>>(qg, kraw, cosb, sinb, ge, qnw, knw, qTb, kTb);
  k_vpost<<<dim3(4096), blk, 0, stream>>>(vraw, ge, vTb);
  k_attn<<<dim3(4096), dim3(64), 0, stream>>>(qTb, kTb, vTb, kbias, qg, ag);
  k_gemm_bt<1><<<dim3(16, 32), blk, 0, stream>>>(ag, WoT, d_out, 4096, 2048, 2048);
}